// Round 9
// baseline (112.230 us; speedup 1.0000x reference)
//
#include <hip/hip_runtime.h>
#include <hip/hip_bf16.h>

#define LL 2048

typedef float f32x16 __attribute__((ext_vector_type(16)));
typedef float f32x4 __attribute__((ext_vector_type(4)));
typedef short short8 __attribute__((ext_vector_type(8)));

__device__ __forceinline__ float exp2_fast(float x) {
    float r;
    asm volatile("v_exp_f32 %0, %1" : "=v"(r) : "v"(x));
    return r;
}

__device__ __forceinline__ float rcp_fast(float x) {
    float r;
    asm("v_rcp_f32 %0, %1" : "=v"(r) : "v"(x));
    return r;
}

// HW packed conversion: D[15:0]=bf16(lo), D[31:16]=bf16(hi). 1 instr for 2.
__device__ __forceinline__ uint32_t cvtpk(float lo, float hi) {
    uint32_t r;
    asm("v_cvt_pk_bf16_f32 %0, %1, %2" : "=v"(r) : "v"(lo), "v"(hi));
    return r;
}

__device__ __forceinline__ unsigned short bf16lo(float a) {
    return (unsigned short)(cvtpk(a, a) & 0xFFFFu);
}

// v_permlane32_swap_b32 D, S:  D_row1 <- S_row0_old ; S_row0 <- D_row1_old.
__device__ __forceinline__ void permswap(uint32_t& d, uint32_t& s) {
    asm("v_permlane32_swap_b32 %0, %1" : "+v"(d), "+v"(s));
}

// ---------------------------------------------------------------------------
// Kernel 1: GroupNorm partial sums (4 blocks per (b,g)) + block 0 fills the
// bf16 ones-buffer (lives directly after vb so k_attn can use one SGPR base).
// ---------------------------------------------------------------------------
__global__ __launch_bounds__(256) void k_gnstats(const float* __restrict__ x,
                                                 float* __restrict__ stats,
                                                 unsigned short* __restrict__ ones) {
    if (blockIdx.x == 0) {
        uint4 v = make_uint4(0x3F803F80u, 0x3F803F80u, 0x3F803F80u, 0x3F803F80u);
        *(uint4*)(ones + threadIdx.x * 16)     = v;
        *(uint4*)(ones + threadIdx.x * 16 + 8) = v;
    }
    int bg = blockIdx.x >> 2, part = blockIdx.x & 3;
    const f32x4* p = (const f32x4*)(x + (size_t)bg * (16 * LL)) + part * 2048;
    float s1 = 0.f, s2 = 0.f;
    for (int i = threadIdx.x; i < 2048; i += 256) {
        f32x4 v = p[i];
        s1 += v[0] + v[1] + v[2] + v[3];
        s2 += v[0] * v[0] + v[1] * v[1] + v[2] * v[2] + v[3] * v[3];
    }
#pragma unroll
    for (int off = 32; off > 0; off >>= 1) {
        s1 += __shfl_down(s1, off, 64);
        s2 += __shfl_down(s2, off, 64);
    }
    __shared__ float r1[4], r2[4];
    int lane = threadIdx.x & 63, wv = threadIdx.x >> 6;
    if (lane == 0) { r1[wv] = s1; r2[wv] = s2; }
    __syncthreads();
    if (threadIdx.x == 0) {
        stats[blockIdx.x * 2]     = r1[0] + r1[1] + r1[2] + r1[3];
        stats[blockIdx.x * 2 + 1] = r2[0] + r2[1] + r2[2] + r2[3];
    }
}

// ---------------------------------------------------------------------------
// Kernel 2: QKV conv1x1 as bf16 MFMA GEMM with fused GroupNorm (as R8).
// Outputs: qt [bh][t][16c] (*0.5), kt [bh][s][16c] (*0.5*log2e),
//          vb [bh][16c][s].  grid (32 lt, 3 ot, 8 b), block 256.
// ---------------------------------------------------------------------------
__global__ __launch_bounds__(256) void k_qkv(const float* __restrict__ x,
                                             const float* __restrict__ gnw,
                                             const float* __restrict__ gnb,
                                             const float* __restrict__ qw,
                                             const float* __restrict__ qb,
                                             const float* __restrict__ stats,
                                             unsigned short* __restrict__ qt,
                                             unsigned short* __restrict__ kt,
                                             unsigned short* __restrict__ vb) {
    int lt = blockIdx.x;   // 0..31
    int ot = blockIdx.y;   // 0..2  (q, k, v)
    int b  = blockIdx.z;   // 0..7
    int tid = threadIdx.x;
    int l0 = lt * 64;
    __shared__ unsigned short xs[64 * 64];   // [l][c], short idx c ^ ((l&7)<<3)
    __shared__ unsigned short ws[64 * 64];   // [o][c], short idx c ^ ((o&7)<<3)
    __shared__ float wb[64][2];              // per-channel wgt, bia

    if (tid < 64) {
        int c = tid, g = c >> 4;
        int sb = (b * 4 + g) * 8;
        float s1 = stats[sb] + stats[sb + 2] + stats[sb + 4] + stats[sb + 6];
        float s2 = stats[sb + 1] + stats[sb + 3] + stats[sb + 5] + stats[sb + 7];
        float mean = s1 * (1.0f / 32768.0f);
        float var  = s2 * (1.0f / 32768.0f) - mean * mean;
        float rstd = rsqrtf(var + 1e-5f);
        float wgt = gnw[c] * rstd;
        wb[c][0] = wgt;
        wb[c][1] = gnb[c] - mean * wgt;
    }
    // weight tile staging (independent of wb)
#pragma unroll
    for (int k = 0; k < 4; k++) {
        int chunk = tid + k * 256;
        int o = chunk >> 4, c4 = chunk & 15;
        f32x4 wv4 = *(const f32x4*)(qw + (size_t)(ot * 64 + o) * 64 + c4 * 4);
        uint2 pw2 = make_uint2(cvtpk(wv4[0], wv4[1]), cvtpk(wv4[2], wv4[3]));
        *(uint2*)&ws[o * 64 + ((c4 * 4) ^ ((o & 7) << 3))] = pw2;
    }
    __syncthreads();   // wb ready

    // x staging: thread = (c-quad, l4-group)
    {
        int cq = tid >> 4, l4 = tid & 15, c0 = cq * 4;
        f32x4 xv0 = *(const f32x4*)(x + ((size_t)b * 64 + c0)     * LL + l0 + l4 * 4);
        f32x4 xv1 = *(const f32x4*)(x + ((size_t)b * 64 + c0 + 1) * LL + l0 + l4 * 4);
        f32x4 xv2 = *(const f32x4*)(x + ((size_t)b * 64 + c0 + 2) * LL + l0 + l4 * 4);
        f32x4 xv3 = *(const f32x4*)(x + ((size_t)b * 64 + c0 + 3) * LL + l0 + l4 * 4);
        float w0 = wb[c0][0], b0 = wb[c0][1];
        float w1 = wb[c0 + 1][0], b1 = wb[c0 + 1][1];
        float w2 = wb[c0 + 2][0], b2 = wb[c0 + 2][1];
        float w3 = wb[c0 + 3][0], b3 = wb[c0 + 3][1];
#pragma unroll
        for (int j = 0; j < 4; j++) {
            int l = l4 * 4 + j;
            uint32_t lo = cvtpk(xv0[j] * w0 + b0, xv1[j] * w1 + b1);
            uint32_t hw = cvtpk(xv2[j] * w2 + b2, xv3[j] * w3 + b3);
            *(uint2*)&xs[l * 64 + (c0 ^ ((l & 7) << 3))] = make_uint2(lo, hw);
        }
    }
    __syncthreads();

    int wv_ = tid >> 6, lane = tid & 63, hi = lane >> 5, tl = lane & 31;
    int o0 = (wv_ & 1) * 32, lw = (wv_ >> 1) * 32;
    int arow = o0 + tl, brow = lw + tl;
    f32x16 acc = {};
#pragma unroll
    for (int kk = 0; kk < 4; kk++) {
        int cb = kk * 16 + hi * 8;
        short8 af = *(const short8*)&ws[arow * 64 + (cb ^ ((arow & 7) << 3))];
        short8 bf = *(const short8*)&xs[brow * 64 + (cb ^ ((brow & 7) << 3))];
        acc = __builtin_amdgcn_mfma_f32_32x32x16_bf16(af, bf, acc, 0, 0, 0);
    }

    int t = l0 + lw + tl;
    if (ot < 2) {
        float sc = ot ? 0.72134752f : 0.5f;   // k also carries log2(e)
        unsigned short* base = (ot ? kt : qt) + (size_t)(b * 4) * (LL * 16);
#pragma unroll
        for (int g = 0; g < 4; g++) {
            int ob = o0 + 8 * g + 4 * hi;
            float v0 = (acc[4 * g]     + qb[ot * 64 + ob])     * sc;
            float v1 = (acc[4 * g + 1] + qb[ot * 64 + ob + 1]) * sc;
            float v2 = (acc[4 * g + 2] + qb[ot * 64 + ob + 2]) * sc;
            float v3 = (acc[4 * g + 3] + qb[ot * 64 + ob + 3]) * sc;
            uint2 pkv = make_uint2(cvtpk(v0, v1), cvtpk(v2, v3));
            *(uint2*)(base + (size_t)(ob >> 4) * (LL * 16) + (size_t)t * 16 + (ob & 15)) = pkv;
        }
    } else {
        unsigned short* base = vb + (size_t)(b * 4) * (16 * LL);
#pragma unroll
        for (int r = 0; r < 16; r++) {
            int o = o0 + (r & 3) + 8 * (r >> 2) + 4 * hi;
            base[(size_t)(o >> 4) * (16 * LL) + (size_t)(o & 15) * LL + t] =
                bf16lo(acc[r] + qb[128 + o]);
        }
    }
}

// ---------------------------------------------------------------------------
// Kernel 3: MFMA flash attention, fixed-max softmax, split-K x4.
// Ping-pong pipeline: QK^T of tile i+1 issued before softmax(tile i); K/V
// prefetched one processing-slot ahead. SGPR-base + 32-bit offsets.
// PV cols 16-31 = ones (lives right after vb) -> lsum on the MFMA pipe.
// grid (64 t-tiles, 32 bh), block 256.
// ---------------------------------------------------------------------------
__global__ __launch_bounds__(256) void k_attn(const unsigned short* __restrict__ qt,
                                              const unsigned short* __restrict__ kt,
                                              const unsigned short* __restrict__ vb,
                                              unsigned short* __restrict__ abuf) {
    int wv = threadIdx.x >> 6;          // split index 0..3
    int lane = threadIdx.x & 63;
    int hi = lane >> 5, tlo = lane & 31;
    int bh = blockIdx.y;
    int t0 = blockIdx.x * 32;

    __shared__ float lds_d2[3][32][33];

    const unsigned short* qp = qt + (size_t)bh * (LL * 16);
    const unsigned short* kbase = kt + (size_t)bh * (LL * 16);
    const unsigned short* vbase = vb + (size_t)bh * (16 * LL);

    // 32-bit offsets from uniform bases. ones sits at vb + 32*16*LL, so the
    // lsum lanes use a block-uniform offset into the same base.
    int koff = (wv * 512 + tlo) * 16 + 8 * hi;
    int voff = (tlo < 16 ? tlo * LL : (32 - bh) * 16 * LL) + wv * 512 + 8 * hi;

    short8 qf = *(const short8*)(qp + (size_t)(t0 + tlo) * 16 + 8 * hi);

    const f32x16 z = {};
    f32x16 d2 = {};

    // prologue: tiles 0 and 1 in flight
    short8 kfa = *(const short8*)&kbase[koff];
    short8 kfb = *(const short8*)&kbase[koff + 512];
    short8 vA0 = *(const short8*)&vbase[voff];
    short8 vA1 = *(const short8*)&vbase[voff + 16];
    short8 vB0 = *(const short8*)&vbase[voff + 32];
    short8 vB1 = *(const short8*)&vbase[voff + 48];
    f32x16 d1A = __builtin_amdgcn_mfma_f32_32x32x16_bf16(kfa, qf, z, 0, 0, 0);
    f32x16 d1B = __builtin_amdgcn_mfma_f32_32x32x16_bf16(kfb, qf, z, 0, 0, 0);

    int kpre = koff + 1024;   // tile 2
    int vpre = voff + 64;

    // softmax + PV of one d1 tile; emits 2 PV MFMAs into d2.
#define SOFTMAX_PV(D1, V0, V1)                                                \
    {                                                                         \
        uint32_t pk0 = cvtpk(exp2_fast(D1[0]),  exp2_fast(D1[1]));            \
        uint32_t pk1 = cvtpk(exp2_fast(D1[2]),  exp2_fast(D1[3]));            \
        uint32_t pk2 = cvtpk(exp2_fast(D1[4]),  exp2_fast(D1[5]));            \
        uint32_t pk3 = cvtpk(exp2_fast(D1[6]),  exp2_fast(D1[7]));            \
        uint32_t pk4 = cvtpk(exp2_fast(D1[8]),  exp2_fast(D1[9]));            \
        uint32_t pk5 = cvtpk(exp2_fast(D1[10]), exp2_fast(D1[11]));           \
        uint32_t pk6 = cvtpk(exp2_fast(D1[12]), exp2_fast(D1[13]));           \
        uint32_t pk7 = cvtpk(exp2_fast(D1[14]), exp2_fast(D1[15]));           \
        permswap(pk0, pk2);                                                   \
        permswap(pk1, pk3);                                                   \
        permswap(pk4, pk6);                                                   \
        permswap(pk5, pk7);                                                   \
        union { uint32_t u[4]; short8 s; } A1_, A2_;                          \
        A1_.u[0] = pk0; A1_.u[1] = pk1; A1_.u[2] = pk2; A1_.u[3] = pk3;       \
        A2_.u[0] = pk4; A2_.u[1] = pk5; A2_.u[2] = pk6; A2_.u[3] = pk7;       \
        d2 = __builtin_amdgcn_mfma_f32_32x32x16_bf16(A1_.s, V0, d2, 0, 0, 0); \
        d2 = __builtin_amdgcn_mfma_f32_32x32x16_bf16(A2_.s, V1, d2, 0, 0, 0); \
    }

#pragma unroll 2
    for (int it = 0; it < 8; ++it) {
        // ---- process tile A (2*it), refill A with tile 2*it+2 ----
        kfa = *(const short8*)&kbase[kpre];
        SOFTMAX_PV(d1A, vA0, vA1)
        vA0 = *(const short8*)&vbase[vpre];
        vA1 = *(const short8*)&vbase[vpre + 16];
        d1A = __builtin_amdgcn_mfma_f32_32x32x16_bf16(kfa, qf, z, 0, 0, 0);
        // ---- process tile B (2*it+1), refill B with tile 2*it+3 ----
        kfb = *(const short8*)&kbase[kpre + 512];
        SOFTMAX_PV(d1B, vB0, vB1)
        vB0 = *(const short8*)&vbase[vpre + 32];
        vB1 = *(const short8*)&vbase[vpre + 48];
        d1B = __builtin_amdgcn_mfma_f32_32x32x16_bf16(kfb, qf, z, 0, 0, 0);
        kpre += 1024;
        vpre += 64;
    }
#undef SOFTMAX_PV

    if (wv > 0) {
        int w = wv - 1;
#pragma unroll
        for (int r = 0; r < 16; r++) {
            int row = (r & 3) + 8 * (r >> 2) + 4 * hi;
            lds_d2[w][row][tlo] = d2[r];   // O cols 0-15, lsum cols 16-31
        }
    }
    __syncthreads();
    if (wv == 0) {
        unsigned short* op = abuf + ((size_t)bh * 16 + tlo) * LL + t0;
        float v[16];
#pragma unroll
        for (int r = 0; r < 16; r++) {
            int row = (r & 3) + 8 * (r >> 2) + 4 * hi;
            float osum = d2[r] + lds_d2[0][row][tlo]
                       + lds_d2[1][row][tlo] + lds_d2[2][row][tlo];
            float rv = rcp_fast(osum);           // meaningful on lanes 16-31
            float rl = __shfl_xor(rv, 16, 64);   // O-lanes fetch rcp(lsum)
            v[r] = osum * rl;
        }
        if (tlo < 16) {
#pragma unroll
            for (int g = 0; g < 4; g++) {
                uint2 pkv = make_uint2(cvtpk(v[4 * g], v[4 * g + 1]),
                                       cvtpk(v[4 * g + 2], v[4 * g + 3]));
                *(uint2*)(op + 8 * g + 4 * hi) = pkv;
            }
        }
    }
}

// ---------------------------------------------------------------------------
// Kernel 4: proj conv1x1 as bf16 MFMA GEMM + bias + fp32 residual (as R8).
// grid (32 lt, 8 b), block 256 (4 waves).
// ---------------------------------------------------------------------------
__global__ __launch_bounds__(256) void k_proj(const float* __restrict__ x,
                                              const unsigned short* __restrict__ abuf,
                                              const float* __restrict__ pw,
                                              const float* __restrict__ pb,
                                              float* __restrict__ out) {
    int lt = blockIdx.x;   // 0..31
    int b  = blockIdx.y;   // 0..7
    int tid = threadIdx.x;
    int l0 = lt * 64;
    __shared__ unsigned short as_[64 * 64];  // [l][c] swizzled
    __shared__ unsigned short ws[64 * 64];   // [o][c] swizzled

    {
        int cq = tid >> 4, t4 = tid & 15, c0 = cq * 4;
        uint2 ld0 = *(const uint2*)(abuf + (size_t)(b * 64 + c0)     * LL + l0 + t4 * 4);
        uint2 ld1 = *(const uint2*)(abuf + (size_t)(b * 64 + c0 + 1) * LL + l0 + t4 * 4);
        uint2 ld2 = *(const uint2*)(abuf + (size_t)(b * 64 + c0 + 2) * LL + l0 + t4 * 4);
        uint2 ld3 = *(const uint2*)(abuf + (size_t)(b * 64 + c0 + 3) * LL + l0 + t4 * 4);
        const unsigned short* s0 = (const unsigned short*)&ld0;
        const unsigned short* s1 = (const unsigned short*)&ld1;
        const unsigned short* s2 = (const unsigned short*)&ld2;
        const unsigned short* s3 = (const unsigned short*)&ld3;
#pragma unroll
        for (int j = 0; j < 4; j++) {
            int l = t4 * 4 + j;
            uint32_t lo = (uint32_t)s0[j] | ((uint32_t)s1[j] << 16);
            uint32_t hw = (uint32_t)s2[j] | ((uint32_t)s3[j] << 16);
            *(uint2*)&as_[l * 64 + (c0 ^ ((l & 7) << 3))] = make_uint2(lo, hw);
        }
    }
#pragma unroll
    for (int k = 0; k < 4; k++) {
        int chunk = tid + k * 256;
        int o = chunk >> 4, c4 = chunk & 15;
        f32x4 wv4 = *(const f32x4*)(pw + (size_t)o * 64 + c4 * 4);
        uint2 pw2 = make_uint2(cvtpk(wv4[0], wv4[1]), cvtpk(wv4[2], wv4[3]));
        *(uint2*)&ws[o * 64 + ((c4 * 4) ^ ((o & 7) << 3))] = pw2;
    }
    __syncthreads();

    int wv_ = tid >> 6, lane = tid & 63, hi = lane >> 5, tl = lane & 31;
    int o0 = (wv_ & 1) * 32, lw = (wv_ >> 1) * 32;
    int arow = o0 + tl, brow = lw + tl;
    f32x16 acc = {};
#pragma unroll
    for (int kk = 0; kk < 4; kk++) {
        int cb = kk * 16 + hi * 8;
        short8 af = *(const short8*)&ws[arow * 64 + (cb ^ ((arow & 7) << 3))];
        short8 bf = *(const short8*)&as_[brow * 64 + (cb ^ ((brow & 7) << 3))];
        acc = __builtin_amdgcn_mfma_f32_32x32x16_bf16(af, bf, acc, 0, 0, 0);
    }

    int l = l0 + lw + tl;
#pragma unroll
    for (int r = 0; r < 16; r++) {
        int o = o0 + (r & 3) + 8 * (r >> 2) + 4 * hi;
        size_t idx = (size_t)(b * 64 + o) * LL + l;
        out[idx] = x[idx] + acc[r] + pb[o];
    }
}

// ---------------------------------------------------------------------------
extern "C" void kernel_launch(void* const* d_in, const int* in_sizes, int n_in,
                              void* d_out, int out_size, void* d_ws, size_t ws_size,
                              hipStream_t stream) {
    const float* x   = (const float*)d_in[0];
    const float* gnw = (const float*)d_in[1];
    const float* gnb = (const float*)d_in[2];
    const float* qw  = (const float*)d_in[3];
    const float* qb  = (const float*)d_in[4];
    const float* pw  = (const float*)d_in[5];
    const float* pb  = (const float*)d_in[6];
    float* out = (float*)d_out;

    float* wsf   = (float*)d_ws;
    float* stats = wsf;                                  // 256 floats (partials)
    unsigned short* qt = (unsigned short*)(wsf + 256);   // 32*2048*16 bf16
    unsigned short* kt = qt + (size_t)32 * LL * 16;
    unsigned short* vb = kt + (size_t)32 * LL * 16;
    unsigned short* ones = vb + (size_t)32 * LL * 16;    // MUST follow vb
    unsigned short* abuf = ones + 4096;                  // 8*64*2048 bf16

    hipLaunchKernelGGL(k_gnstats, dim3(128), dim3(256), 0, stream, x, stats, ones);
    hipLaunchKernelGGL(k_qkv, dim3(32, 3, 8), dim3(256), 0, stream,
                       x, gnw, gnb, qw, qb, stats, qt, kt, vb);
    hipLaunchKernelGGL(k_attn, dim3(64, 32), dim3(256), 0, stream,
                       qt, kt, vb, abuf);
    hipLaunchKernelGGL(k_proj, dim3(32, 8), dim3(256), 0, stream,
                       x, abuf, pw, pb, out);
}

// Round 10
// 110.600 us; speedup vs baseline: 1.0147x; 1.0147x over previous
//
#include <hip/hip_runtime.h>
#include <hip/hip_bf16.h>

#define LL 2048

typedef float f32x16 __attribute__((ext_vector_type(16)));
typedef float f32x4 __attribute__((ext_vector_type(4)));
typedef short short8 __attribute__((ext_vector_type(8)));

__device__ __forceinline__ float exp2_fast(float x) {
    float r;
    asm volatile("v_exp_f32 %0, %1" : "=v"(r) : "v"(x));
    return r;
}

__device__ __forceinline__ float rcp_fast(float x) {
    float r;
    asm("v_rcp_f32 %0, %1" : "=v"(r) : "v"(x));
    return r;
}

// HW packed conversion: D[15:0]=bf16(lo), D[31:16]=bf16(hi). 1 instr for 2.
__device__ __forceinline__ uint32_t cvtpk(float lo, float hi) {
    uint32_t r;
    asm("v_cvt_pk_bf16_f32 %0, %1, %2" : "=v"(r) : "v"(lo), "v"(hi));
    return r;
}

__device__ __forceinline__ unsigned short bf16lo(float a) {
    return (unsigned short)(cvtpk(a, a) & 0xFFFFu);
}

// v_permlane32_swap_b32 D, S:  D_row1 <- S_row0_old ; S_row0 <- D_row1_old.
__device__ __forceinline__ void permswap(uint32_t& d, uint32_t& s) {
    asm("v_permlane32_swap_b32 %0, %1" : "+v"(d), "+v"(s));
}

// ---------------------------------------------------------------------------
// Kernel 1: GroupNorm partial sums (4 blocks per (b,g)). Side jobs:
//   block 0      -> fill bf16 ones buffer (k_attn lsum trick)
//   blocks 8-15  -> convert qkv+proj weights f32 -> bf16 once (wqb | wpb)
// ---------------------------------------------------------------------------
__global__ __launch_bounds__(256) void k_gnstats(const float* __restrict__ x,
                                                 const float* __restrict__ qw,
                                                 const float* __restrict__ pw,
                                                 float* __restrict__ stats,
                                                 unsigned short* __restrict__ ones,
                                                 unsigned short* __restrict__ wqb) {
    if (blockIdx.x == 0) {
        uint4 v = make_uint4(0x3F803F80u, 0x3F803F80u, 0x3F803F80u, 0x3F803F80u);
        *(uint4*)(ones + threadIdx.x * 16)     = v;
        *(uint4*)(ones + threadIdx.x * 16 + 8) = v;
    }
    if (blockIdx.x >= 8 && blockIdx.x < 16) {
        // 16384 weights total: qw (12288) then pw (4096); 8 f32 per thread.
        int idx8 = (blockIdx.x - 8) * 2048 + threadIdx.x * 8;
        const float* src = (idx8 < 12288) ? qw + idx8 : pw + (idx8 - 12288);
        f32x4 a = *(const f32x4*)src;
        f32x4 c = *(const f32x4*)(src + 4);
        uint4 o = make_uint4(cvtpk(a[0], a[1]), cvtpk(a[2], a[3]),
                             cvtpk(c[0], c[1]), cvtpk(c[2], c[3]));
        *(uint4*)(wqb + idx8) = o;
    }
    int bg = blockIdx.x >> 2, part = blockIdx.x & 3;
    const f32x4* p = (const f32x4*)(x + (size_t)bg * (16 * LL)) + part * 2048;
    float s1 = 0.f, s2 = 0.f;
    for (int i = threadIdx.x; i < 2048; i += 256) {
        f32x4 v = p[i];
        s1 += v[0] + v[1] + v[2] + v[3];
        s2 += v[0] * v[0] + v[1] * v[1] + v[2] * v[2] + v[3] * v[3];
    }
#pragma unroll
    for (int off = 32; off > 0; off >>= 1) {
        s1 += __shfl_down(s1, off, 64);
        s2 += __shfl_down(s2, off, 64);
    }
    __shared__ float r1[4], r2[4];
    int lane = threadIdx.x & 63, wv = threadIdx.x >> 6;
    if (lane == 0) { r1[wv] = s1; r2[wv] = s2; }
    __syncthreads();
    if (threadIdx.x == 0) {
        stats[blockIdx.x * 2]     = r1[0] + r1[1] + r1[2] + r1[3];
        stats[blockIdx.x * 2 + 1] = r2[0] + r2[1] + r2[2] + r2[3];
    }
}

// ---------------------------------------------------------------------------
// Kernel 2: QKV conv1x1 as bf16 MFMA GEMM with fused GroupNorm.
// ONE block per (lt,b) computes q,k,v: x staged once, 3 pre-converted bf16
// weight tiles, 3x4 MFMAs. Outputs: qt [bh][t][16c] (*0.5),
// kt [bh][s][16c] (*0.5*log2e), vb [bh][16c][s]. grid (32,8), block 256.
// ---------------------------------------------------------------------------
__global__ __launch_bounds__(256) void k_qkv(const float* __restrict__ x,
                                             const float* __restrict__ gnw,
                                             const float* __restrict__ gnb,
                                             const unsigned short* __restrict__ wqb,
                                             const float* __restrict__ qb,
                                             const float* __restrict__ stats,
                                             unsigned short* __restrict__ qt,
                                             unsigned short* __restrict__ kt,
                                             unsigned short* __restrict__ vb) {
    int lt = blockIdx.x;   // 0..31
    int b  = blockIdx.y;   // 0..7
    int tid = threadIdx.x;
    int l0 = lt * 64;
    __shared__ unsigned short xs[64 * 64];      // [l][c], idx c ^ ((l&7)<<3)
    __shared__ unsigned short ws[3][64 * 64];   // [o][c], idx c ^ ((o&7)<<3)
    __shared__ float wb[64][2];                 // per-channel wgt, bia

    if (tid < 64) {
        int c = tid, g = c >> 4;
        int sb = (b * 4 + g) * 8;
        float s1 = stats[sb] + stats[sb + 2] + stats[sb + 4] + stats[sb + 6];
        float s2 = stats[sb + 1] + stats[sb + 3] + stats[sb + 5] + stats[sb + 7];
        float mean = s1 * (1.0f / 32768.0f);
        float var  = s2 * (1.0f / 32768.0f) - mean * mean;
        float rstd = rsqrtf(var + 1e-5f);
        float wgt = gnw[c] * rstd;
        wb[c][0] = wgt;
        wb[c][1] = gnb[c] - mean * wgt;
    }
    // weight tiles: already bf16, straight uint2 copies into swizzled LDS
#pragma unroll
    for (int ot = 0; ot < 3; ot++) {
#pragma unroll
        for (int k = 0; k < 4; k++) {
            int chunk = tid + k * 256;
            int o = chunk >> 4, c4 = chunk & 15;
            uint2 w2 = *(const uint2*)(wqb + (size_t)(ot * 64 + o) * 64 + c4 * 4);
            *(uint2*)&ws[ot][o * 64 + ((c4 * 4) ^ ((o & 7) << 3))] = w2;
        }
    }
    __syncthreads();   // wb ready

    // x staging: thread = (c-quad, l4-group), GN applied on the fly
    {
        int cq = tid >> 4, l4 = tid & 15, c0 = cq * 4;
        f32x4 xv0 = *(const f32x4*)(x + ((size_t)b * 64 + c0)     * LL + l0 + l4 * 4);
        f32x4 xv1 = *(const f32x4*)(x + ((size_t)b * 64 + c0 + 1) * LL + l0 + l4 * 4);
        f32x4 xv2 = *(const f32x4*)(x + ((size_t)b * 64 + c0 + 2) * LL + l0 + l4 * 4);
        f32x4 xv3 = *(const f32x4*)(x + ((size_t)b * 64 + c0 + 3) * LL + l0 + l4 * 4);
        float w0 = wb[c0][0], b0 = wb[c0][1];
        float w1 = wb[c0 + 1][0], b1 = wb[c0 + 1][1];
        float w2 = wb[c0 + 2][0], b2 = wb[c0 + 2][1];
        float w3 = wb[c0 + 3][0], b3 = wb[c0 + 3][1];
#pragma unroll
        for (int j = 0; j < 4; j++) {
            int l = l4 * 4 + j;
            uint32_t lo = cvtpk(xv0[j] * w0 + b0, xv1[j] * w1 + b1);
            uint32_t hw = cvtpk(xv2[j] * w2 + b2, xv3[j] * w3 + b3);
            *(uint2*)&xs[l * 64 + (c0 ^ ((l & 7) << 3))] = make_uint2(lo, hw);
        }
    }
    __syncthreads();

    int wv_ = tid >> 6, lane = tid & 63, hi = lane >> 5, tl = lane & 31;
    int o0 = (wv_ & 1) * 32, lw = (wv_ >> 1) * 32;
    int arow = o0 + tl, brow = lw + tl;
    int t = l0 + lw + tl;

#pragma unroll
    for (int ot = 0; ot < 3; ot++) {
        f32x16 acc = {};
#pragma unroll
        for (int kk = 0; kk < 4; kk++) {
            int cb = kk * 16 + hi * 8;
            short8 af = *(const short8*)&ws[ot][arow * 64 + (cb ^ ((arow & 7) << 3))];
            short8 bf = *(const short8*)&xs[brow * 64 + (cb ^ ((brow & 7) << 3))];
            acc = __builtin_amdgcn_mfma_f32_32x32x16_bf16(af, bf, acc, 0, 0, 0);
        }
        if (ot < 2) {
            float sc = ot ? 0.72134752f : 0.5f;   // k also carries log2(e)
            unsigned short* base = (ot ? kt : qt) + (size_t)(b * 4) * (LL * 16);
#pragma unroll
            for (int g = 0; g < 4; g++) {
                int ob = o0 + 8 * g + 4 * hi;
                float v0 = (acc[4 * g]     + qb[ot * 64 + ob])     * sc;
                float v1 = (acc[4 * g + 1] + qb[ot * 64 + ob + 1]) * sc;
                float v2 = (acc[4 * g + 2] + qb[ot * 64 + ob + 2]) * sc;
                float v3 = (acc[4 * g + 3] + qb[ot * 64 + ob + 3]) * sc;
                uint2 pkv = make_uint2(cvtpk(v0, v1), cvtpk(v2, v3));
                *(uint2*)(base + (size_t)(ob >> 4) * (LL * 16)
                          + (size_t)t * 16 + (ob & 15)) = pkv;
            }
        } else {
            unsigned short* base = vb + (size_t)(b * 4) * (16 * LL);
#pragma unroll
            for (int r = 0; r < 16; r++) {
                int o = o0 + (r & 3) + 8 * (r >> 2) + 4 * hi;
                base[(size_t)(o >> 4) * (16 * LL) + (size_t)(o & 15) * LL + t] =
                    bf16lo(acc[r] + qb[128 + o]);
            }
        }
    }
}

// ---------------------------------------------------------------------------
// Kernel 3: MFMA flash attention (unchanged from R9): fixed-max softmax,
// split-K x4, ping-pong pipeline, SGPR-base + 32-bit offsets, lsum via
// ones-columns on the MFMA pipe. grid (64 t-tiles, 32 bh), block 256.
// ---------------------------------------------------------------------------
__global__ __launch_bounds__(256) void k_attn(const unsigned short* __restrict__ qt,
                                              const unsigned short* __restrict__ kt,
                                              const unsigned short* __restrict__ vb,
                                              unsigned short* __restrict__ abuf) {
    int wv = threadIdx.x >> 6;          // split index 0..3
    int lane = threadIdx.x & 63;
    int hi = lane >> 5, tlo = lane & 31;
    int bh = blockIdx.y;
    int t0 = blockIdx.x * 32;

    __shared__ float lds_d2[3][32][33];

    const unsigned short* qp = qt + (size_t)bh * (LL * 16);
    const unsigned short* kbase = kt + (size_t)bh * (LL * 16);
    const unsigned short* vbase = vb + (size_t)bh * (16 * LL);

    int koff = (wv * 512 + tlo) * 16 + 8 * hi;
    int voff = (tlo < 16 ? tlo * LL : (32 - bh) * 16 * LL) + wv * 512 + 8 * hi;

    short8 qf = *(const short8*)(qp + (size_t)(t0 + tlo) * 16 + 8 * hi);

    const f32x16 z = {};
    f32x16 d2 = {};

    short8 kfa = *(const short8*)&kbase[koff];
    short8 kfb = *(const short8*)&kbase[koff + 512];
    short8 vA0 = *(const short8*)&vbase[voff];
    short8 vA1 = *(const short8*)&vbase[voff + 16];
    short8 vB0 = *(const short8*)&vbase[voff + 32];
    short8 vB1 = *(const short8*)&vbase[voff + 48];
    f32x16 d1A = __builtin_amdgcn_mfma_f32_32x32x16_bf16(kfa, qf, z, 0, 0, 0);
    f32x16 d1B = __builtin_amdgcn_mfma_f32_32x32x16_bf16(kfb, qf, z, 0, 0, 0);

    int kpre = koff + 1024;
    int vpre = voff + 64;

#define SOFTMAX_PV(D1, V0, V1)                                                \
    {                                                                         \
        uint32_t pk0 = cvtpk(exp2_fast(D1[0]),  exp2_fast(D1[1]));            \
        uint32_t pk1 = cvtpk(exp2_fast(D1[2]),  exp2_fast(D1[3]));            \
        uint32_t pk2 = cvtpk(exp2_fast(D1[4]),  exp2_fast(D1[5]));            \
        uint32_t pk3 = cvtpk(exp2_fast(D1[6]),  exp2_fast(D1[7]));            \
        uint32_t pk4 = cvtpk(exp2_fast(D1[8]),  exp2_fast(D1[9]));            \
        uint32_t pk5 = cvtpk(exp2_fast(D1[10]), exp2_fast(D1[11]));           \
        uint32_t pk6 = cvtpk(exp2_fast(D1[12]), exp2_fast(D1[13]));           \
        uint32_t pk7 = cvtpk(exp2_fast(D1[14]), exp2_fast(D1[15]));           \
        permswap(pk0, pk2);                                                   \
        permswap(pk1, pk3);                                                   \
        permswap(pk4, pk6);                                                   \
        permswap(pk5, pk7);                                                   \
        union { uint32_t u[4]; short8 s; } A1_, A2_;                          \
        A1_.u[0] = pk0; A1_.u[1] = pk1; A1_.u[2] = pk2; A1_.u[3] = pk3;       \
        A2_.u[0] = pk4; A2_.u[1] = pk5; A2_.u[2] = pk6; A2_.u[3] = pk7;       \
        d2 = __builtin_amdgcn_mfma_f32_32x32x16_bf16(A1_.s, V0, d2, 0, 0, 0); \
        d2 = __builtin_amdgcn_mfma_f32_32x32x16_bf16(A2_.s, V1, d2, 0, 0, 0); \
    }

#pragma unroll 2
    for (int it = 0; it < 8; ++it) {
        kfa = *(const short8*)&kbase[kpre];
        SOFTMAX_PV(d1A, vA0, vA1)
        vA0 = *(const short8*)&vbase[vpre];
        vA1 = *(const short8*)&vbase[vpre + 16];
        d1A = __builtin_amdgcn_mfma_f32_32x32x16_bf16(kfa, qf, z, 0, 0, 0);
        kfb = *(const short8*)&kbase[kpre + 512];
        SOFTMAX_PV(d1B, vB0, vB1)
        vB0 = *(const short8*)&vbase[vpre + 32];
        vB1 = *(const short8*)&vbase[vpre + 48];
        d1B = __builtin_amdgcn_mfma_f32_32x32x16_bf16(kfb, qf, z, 0, 0, 0);
        kpre += 1024;
        vpre += 64;
    }
#undef SOFTMAX_PV

    if (wv > 0) {
        int w = wv - 1;
#pragma unroll
        for (int r = 0; r < 16; r++) {
            int row = (r & 3) + 8 * (r >> 2) + 4 * hi;
            lds_d2[w][row][tlo] = d2[r];   // O cols 0-15, lsum cols 16-31
        }
    }
    __syncthreads();
    if (wv == 0) {
        unsigned short* op = abuf + ((size_t)bh * 16 + tlo) * LL + t0;
        float v[16];
#pragma unroll
        for (int r = 0; r < 16; r++) {
            int row = (r & 3) + 8 * (r >> 2) + 4 * hi;
            float osum = d2[r] + lds_d2[0][row][tlo]
                       + lds_d2[1][row][tlo] + lds_d2[2][row][tlo];
            float rv = rcp_fast(osum);           // meaningful on lanes 16-31
            float rl = __shfl_xor(rv, 16, 64);   // O-lanes fetch rcp(lsum)
            v[r] = osum * rl;
        }
        if (tlo < 16) {
#pragma unroll
            for (int g = 0; g < 4; g++) {
                uint2 pkv = make_uint2(cvtpk(v[4 * g], v[4 * g + 1]),
                                       cvtpk(v[4 * g + 2], v[4 * g + 3]));
                *(uint2*)(op + 8 * g + 4 * hi) = pkv;
            }
        }
    }
}

// ---------------------------------------------------------------------------
// Kernel 4: proj conv1x1 as bf16 MFMA GEMM + bias + fp32 residual.
// Weights pre-converted (wpb). grid (32 lt, 8 b), block 256 (4 waves).
// ---------------------------------------------------------------------------
__global__ __launch_bounds__(256) void k_proj(const float* __restrict__ x,
                                              const unsigned short* __restrict__ abuf,
                                              const unsigned short* __restrict__ wpb,
                                              const float* __restrict__ pb,
                                              float* __restrict__ out) {
    int lt = blockIdx.x;   // 0..31
    int b  = blockIdx.y;   // 0..7
    int tid = threadIdx.x;
    int l0 = lt * 64;
    __shared__ unsigned short as_[64 * 64];  // [l][c] swizzled
    __shared__ unsigned short ws[64 * 64];   // [o][c] swizzled

    {
        int cq = tid >> 4, t4 = tid & 15, c0 = cq * 4;
        uint2 ld0 = *(const uint2*)(abuf + (size_t)(b * 64 + c0)     * LL + l0 + t4 * 4);
        uint2 ld1 = *(const uint2*)(abuf + (size_t)(b * 64 + c0 + 1) * LL + l0 + t4 * 4);
        uint2 ld2 = *(const uint2*)(abuf + (size_t)(b * 64 + c0 + 2) * LL + l0 + t4 * 4);
        uint2 ld3 = *(const uint2*)(abuf + (size_t)(b * 64 + c0 + 3) * LL + l0 + t4 * 4);
        const unsigned short* s0 = (const unsigned short*)&ld0;
        const unsigned short* s1 = (const unsigned short*)&ld1;
        const unsigned short* s2 = (const unsigned short*)&ld2;
        const unsigned short* s3 = (const unsigned short*)&ld3;
#pragma unroll
        for (int j = 0; j < 4; j++) {
            int l = t4 * 4 + j;
            uint32_t lo = (uint32_t)s0[j] | ((uint32_t)s1[j] << 16);
            uint32_t hw = (uint32_t)s2[j] | ((uint32_t)s3[j] << 16);
            *(uint2*)&as_[l * 64 + (c0 ^ ((l & 7) << 3))] = make_uint2(lo, hw);
        }
    }
#pragma unroll
    for (int k = 0; k < 4; k++) {
        int chunk = tid + k * 256;
        int o = chunk >> 4, c4 = chunk & 15;
        uint2 w2 = *(const uint2*)(wpb + (size_t)o * 64 + c4 * 4);
        *(uint2*)&ws[o * 64 + ((c4 * 4) ^ ((o & 7) << 3))] = w2;
    }
    __syncthreads();

    int wv_ = tid >> 6, lane = tid & 63, hi = lane >> 5, tl = lane & 31;
    int o0 = (wv_ & 1) * 32, lw = (wv_ >> 1) * 32;
    int arow = o0 + tl, brow = lw + tl;
    f32x16 acc = {};
#pragma unroll
    for (int kk = 0; kk < 4; kk++) {
        int cb = kk * 16 + hi * 8;
        short8 af = *(const short8*)&ws[arow * 64 + (cb ^ ((arow & 7) << 3))];
        short8 bf = *(const short8*)&as_[brow * 64 + (cb ^ ((brow & 7) << 3))];
        acc = __builtin_amdgcn_mfma_f32_32x32x16_bf16(af, bf, acc, 0, 0, 0);
    }

    int l = l0 + lw + tl;
#pragma unroll
    for (int r = 0; r < 16; r++) {
        int o = o0 + (r & 3) + 8 * (r >> 2) + 4 * hi;
        size_t idx = (size_t)(b * 64 + o) * LL + l;
        out[idx] = x[idx] + acc[r] + pb[o];
    }
}

// ---------------------------------------------------------------------------
extern "C" void kernel_launch(void* const* d_in, const int* in_sizes, int n_in,
                              void* d_out, int out_size, void* d_ws, size_t ws_size,
                              hipStream_t stream) {
    const float* x   = (const float*)d_in[0];
    const float* gnw = (const float*)d_in[1];
    const float* gnb = (const float*)d_in[2];
    const float* qw  = (const float*)d_in[3];
    const float* qb  = (const float*)d_in[4];
    const float* pw  = (const float*)d_in[5];
    const float* pb  = (const float*)d_in[6];
    float* out = (float*)d_out;

    float* wsf   = (float*)d_ws;
    float* stats = wsf;                                  // 256 floats (partials)
    unsigned short* qt = (unsigned short*)(wsf + 256);   // 32*2048*16 bf16
    unsigned short* kt = qt + (size_t)32 * LL * 16;
    unsigned short* vb = kt + (size_t)32 * LL * 16;
    unsigned short* ones = vb + (size_t)32 * LL * 16;    // MUST follow vb
    unsigned short* abuf = ones + 4096;                  // 8*64*2048 bf16
    unsigned short* wqb  = abuf + (size_t)8 * 64 * LL;   // 12288 bf16 (qkv w)
    unsigned short* wpb  = wqb + 12288;                  // 4096 bf16 (proj w)

    hipLaunchKernelGGL(k_gnstats, dim3(128), dim3(256), 0, stream,
                       x, qw, pw, stats, ones, wqb);
    hipLaunchKernelGGL(k_qkv, dim3(32, 8), dim3(256), 0, stream,
                       x, gnw, gnb, wqb, qb, stats, qt, kt, vb);
    hipLaunchKernelGGL(k_attn, dim3(64, 32), dim3(256), 0, stream,
                       qt, kt, vb, abuf);
    hipLaunchKernelGGL(k_proj, dim3(32, 8), dim3(256), 0, stream,
                       x, abuf, wpb, pb, out);
}

// Round 12
// 105.922 us; speedup vs baseline: 1.0596x; 1.0442x over previous
//
#include <hip/hip_runtime.h>
#include <hip/hip_bf16.h>

#define LL 2048

typedef float f32x16 __attribute__((ext_vector_type(16)));
typedef float f32x4 __attribute__((ext_vector_type(4)));
typedef short short8 __attribute__((ext_vector_type(8)));

__device__ __forceinline__ float exp2_fast(float x) {
    float r;
    asm volatile("v_exp_f32 %0, %1" : "=v"(r) : "v"(x));
    return r;
}

__device__ __forceinline__ float rcp_fast(float x) {
    float r;
    asm("v_rcp_f32 %0, %1" : "=v"(r) : "v"(x));
    return r;
}

// HW packed conversion: D[15:0]=bf16(lo), D[31:16]=bf16(hi). 1 instr for 2.
__device__ __forceinline__ uint32_t cvtpk(float lo, float hi) {
    uint32_t r;
    asm("v_cvt_pk_bf16_f32 %0, %1, %2" : "=v"(r) : "v"(lo), "v"(hi));
    return r;
}

__device__ __forceinline__ unsigned short bf16lo(float a) {
    return (unsigned short)(cvtpk(a, a) & 0xFFFFu);
}

// v_permlane32_swap_b32 D, S:  D_row1 <- S_row0_old ; S_row0 <- D_row1_old.
__device__ __forceinline__ void permswap(uint32_t& d, uint32_t& s) {
    asm("v_permlane32_swap_b32 %0, %1" : "+v"(d), "+v"(s));
}

// ---------------------------------------------------------------------------
// Kernel 1: GroupNorm partial sums (4 blocks per (b,g)). Side jobs:
//   block 0      -> fill bf16 ones buffer (lsum trick)
//   blocks 8-15  -> convert qkv+proj weights f32 -> bf16 once (wqb | wpb)
// ---------------------------------------------------------------------------
__global__ __launch_bounds__(256) void k_gnstats(const float* __restrict__ x,
                                                 const float* __restrict__ qw,
                                                 const float* __restrict__ pw,
                                                 float* __restrict__ stats,
                                                 unsigned short* __restrict__ ones,
                                                 unsigned short* __restrict__ wqb) {
    if (blockIdx.x == 0) {
        uint4 v = make_uint4(0x3F803F80u, 0x3F803F80u, 0x3F803F80u, 0x3F803F80u);
        *(uint4*)(ones + threadIdx.x * 16)     = v;
        *(uint4*)(ones + threadIdx.x * 16 + 8) = v;
    }
    if (blockIdx.x >= 8 && blockIdx.x < 16) {
        int idx8 = (blockIdx.x - 8) * 2048 + threadIdx.x * 8;
        const float* src = (idx8 < 12288) ? qw + idx8 : pw + (idx8 - 12288);
        f32x4 a = *(const f32x4*)src;
        f32x4 c = *(const f32x4*)(src + 4);
        uint4 o = make_uint4(cvtpk(a[0], a[1]), cvtpk(a[2], a[3]),
                             cvtpk(c[0], c[1]), cvtpk(c[2], c[3]));
        *(uint4*)(wqb + idx8) = o;
    }
    int bg = blockIdx.x >> 2, part = blockIdx.x & 3;
    const f32x4* p = (const f32x4*)(x + (size_t)bg * (16 * LL)) + part * 2048;
    float s1 = 0.f, s2 = 0.f;
    for (int i = threadIdx.x; i < 2048; i += 256) {
        f32x4 v = p[i];
        s1 += v[0] + v[1] + v[2] + v[3];
        s2 += v[0] * v[0] + v[1] * v[1] + v[2] * v[2] + v[3] * v[3];
    }
#pragma unroll
    for (int off = 32; off > 0; off >>= 1) {
        s1 += __shfl_down(s1, off, 64);
        s2 += __shfl_down(s2, off, 64);
    }
    __shared__ float r1[4], r2[4];
    int lane = threadIdx.x & 63, wv = threadIdx.x >> 6;
    if (lane == 0) { r1[wv] = s1; r2[wv] = s2; }
    __syncthreads();
    if (threadIdx.x == 0) {
        stats[blockIdx.x * 2]     = r1[0] + r1[1] + r1[2] + r1[3];
        stats[blockIdx.x * 2 + 1] = r2[0] + r2[1] + r2[2] + r2[3];
    }
}

// ---------------------------------------------------------------------------
// Kernel 2: QKV conv1x1 as bf16 MFMA GEMM with fused GroupNorm (as R10).
// grid (32,8), block 256.
// ---------------------------------------------------------------------------
__global__ __launch_bounds__(256) void k_qkv(const float* __restrict__ x,
                                             const float* __restrict__ gnw,
                                             const float* __restrict__ gnb,
                                             const unsigned short* __restrict__ wqb,
                                             const float* __restrict__ qb,
                                             const float* __restrict__ stats,
                                             unsigned short* __restrict__ qt,
                                             unsigned short* __restrict__ kt,
                                             unsigned short* __restrict__ vb) {
    int lt = blockIdx.x;   // 0..31
    int b  = blockIdx.y;   // 0..7
    int tid = threadIdx.x;
    int l0 = lt * 64;
    __shared__ unsigned short xs[64 * 64];      // [l][c], idx c ^ ((l&7)<<3)
    __shared__ unsigned short ws[3][64 * 64];   // [o][c], idx c ^ ((o&7)<<3)
    __shared__ float wb[64][2];                 // per-channel wgt, bia

    if (tid < 64) {
        int c = tid, g = c >> 4;
        int sb = (b * 4 + g) * 8;
        float s1 = stats[sb] + stats[sb + 2] + stats[sb + 4] + stats[sb + 6];
        float s2 = stats[sb + 1] + stats[sb + 3] + stats[sb + 5] + stats[sb + 7];
        float mean = s1 * (1.0f / 32768.0f);
        float var  = s2 * (1.0f / 32768.0f) - mean * mean;
        float rstd = rsqrtf(var + 1e-5f);
        float wgt = gnw[c] * rstd;
        wb[c][0] = wgt;
        wb[c][1] = gnb[c] - mean * wgt;
    }
#pragma unroll
    for (int ot = 0; ot < 3; ot++) {
#pragma unroll
        for (int k = 0; k < 4; k++) {
            int chunk = tid + k * 256;
            int o = chunk >> 4, c4 = chunk & 15;
            uint2 w2 = *(const uint2*)(wqb + (size_t)(ot * 64 + o) * 64 + c4 * 4);
            *(uint2*)&ws[ot][o * 64 + ((c4 * 4) ^ ((o & 7) << 3))] = w2;
        }
    }
    __syncthreads();   // wb ready

    {
        int cq = tid >> 4, l4 = tid & 15, c0 = cq * 4;
        f32x4 xv0 = *(const f32x4*)(x + ((size_t)b * 64 + c0)     * LL + l0 + l4 * 4);
        f32x4 xv1 = *(const f32x4*)(x + ((size_t)b * 64 + c0 + 1) * LL + l0 + l4 * 4);
        f32x4 xv2 = *(const f32x4*)(x + ((size_t)b * 64 + c0 + 2) * LL + l0 + l4 * 4);
        f32x4 xv3 = *(const f32x4*)(x + ((size_t)b * 64 + c0 + 3) * LL + l0 + l4 * 4);
        float w0 = wb[c0][0], b0 = wb[c0][1];
        float w1 = wb[c0 + 1][0], b1 = wb[c0 + 1][1];
        float w2 = wb[c0 + 2][0], b2 = wb[c0 + 2][1];
        float w3 = wb[c0 + 3][0], b3 = wb[c0 + 3][1];
#pragma unroll
        for (int j = 0; j < 4; j++) {
            int l = l4 * 4 + j;
            uint32_t lo = cvtpk(xv0[j] * w0 + b0, xv1[j] * w1 + b1);
            uint32_t hw = cvtpk(xv2[j] * w2 + b2, xv3[j] * w3 + b3);
            *(uint2*)&xs[l * 64 + (c0 ^ ((l & 7) << 3))] = make_uint2(lo, hw);
        }
    }
    __syncthreads();

    int wv_ = tid >> 6, lane = tid & 63, hi = lane >> 5, tl = lane & 31;
    int o0 = (wv_ & 1) * 32, lw = (wv_ >> 1) * 32;
    int arow = o0 + tl, brow = lw + tl;
    int t = l0 + lw + tl;

#pragma unroll
    for (int ot = 0; ot < 3; ot++) {
        f32x16 acc = {};
#pragma unroll
        for (int kk = 0; kk < 4; kk++) {
            int cb = kk * 16 + hi * 8;
            short8 af = *(const short8*)&ws[ot][arow * 64 + (cb ^ ((arow & 7) << 3))];
            short8 bf = *(const short8*)&xs[brow * 64 + (cb ^ ((brow & 7) << 3))];
            acc = __builtin_amdgcn_mfma_f32_32x32x16_bf16(af, bf, acc, 0, 0, 0);
        }
        if (ot < 2) {
            float sc = ot ? 0.72134752f : 0.5f;   // k also carries log2(e)
            unsigned short* base = (ot ? kt : qt) + (size_t)(b * 4) * (LL * 16);
#pragma unroll
            for (int g = 0; g < 4; g++) {
                int ob = o0 + 8 * g + 4 * hi;
                float v0 = (acc[4 * g]     + qb[ot * 64 + ob])     * sc;
                float v1 = (acc[4 * g + 1] + qb[ot * 64 + ob + 1]) * sc;
                float v2 = (acc[4 * g + 2] + qb[ot * 64 + ob + 2]) * sc;
                float v3 = (acc[4 * g + 3] + qb[ot * 64 + ob + 3]) * sc;
                uint2 pkv = make_uint2(cvtpk(v0, v1), cvtpk(v2, v3));
                *(uint2*)(base + (size_t)(ob >> 4) * (LL * 16)
                          + (size_t)t * 16 + (ob & 15)) = pkv;
            }
        } else {
            unsigned short* base = vb + (size_t)(b * 4) * (16 * LL);
#pragma unroll
            for (int r = 0; r < 16; r++) {
                int o = o0 + (r & 3) + 8 * (r >> 2) + 4 * hi;
                base[(size_t)(o >> 4) * (16 * LL) + (size_t)(o & 15) * LL + t] =
                    bf16lo(acc[r] + qb[128 + o]);
            }
        }
    }
}

// ---------------------------------------------------------------------------
// Kernel 3: FUSED attention + proj. Block = 16 waves (1024 thr) = 4 heads x
// 4 s-splits for one (b, t0). Main loop per wave identical to R10. Epilogue:
// per-head combine -> normalized bf16 O staged [t][c] in LDS -> 2 waves run
// the 64x64x32 proj GEMM + bias + fp32 residual -> out. No abuf, no k_proj.
// grid (64 t-tiles, 8 b), block 1024.
// ---------------------------------------------------------------------------
__global__ __launch_bounds__(1024) void k_attn(const unsigned short* __restrict__ qt,
                                               const unsigned short* __restrict__ kt,
                                               const unsigned short* __restrict__ vb,
                                               const unsigned short* __restrict__ wpb,
                                               const float* __restrict__ pb,
                                               const float* __restrict__ x,
                                               float* __restrict__ out) {
    int tid = threadIdx.x;
    int wv = tid >> 6;                  // 0..15
    int h  = wv >> 2;                   // head 0..3
    int sp = wv & 3;                    // s-split 0..3
    int lane = tid & 63;
    int hi = lane >> 5, tlo = lane & 31;
    int b = blockIdx.y;
    int bh = b * 4 + h;
    int t0 = blockIdx.x * 32;

    __shared__ float lds_d2[4][3][32][33];
    __shared__ unsigned short ostage[32 * 68];   // [t][c], pitch 68
    __shared__ unsigned short wsh[64 * 64];      // proj w [o][c] swizzled

    // stage proj weights (bf16 pre-converted): 1024 threads cover 64x64/4
    {
        int o = tid >> 4, c4 = tid & 15;
        uint2 w2 = *(const uint2*)(wpb + (size_t)o * 64 + c4 * 4);
        *(uint2*)&wsh[o * 64 + ((c4 * 4) ^ ((o & 7) << 3))] = w2;
    }

    const unsigned short* qp = qt + (size_t)bh * (LL * 16);
    const unsigned short* kbase = kt + (size_t)bh * (LL * 16);
    const unsigned short* vbase = vb + (size_t)bh * (16 * LL);

    int koff = (sp * 512 + tlo) * 16 + 8 * hi;
    int voff = (tlo < 16 ? tlo * LL : (32 - bh) * 16 * LL) + sp * 512 + 8 * hi;

    short8 qf = *(const short8*)(qp + (size_t)(t0 + tlo) * 16 + 8 * hi);

    const f32x16 z = {};
    f32x16 d2 = {};

    short8 kfa = *(const short8*)&kbase[koff];
    short8 kfb = *(const short8*)&kbase[koff + 512];
    short8 vA0 = *(const short8*)&vbase[voff];
    short8 vA1 = *(const short8*)&vbase[voff + 16];
    short8 vB0 = *(const short8*)&vbase[voff + 32];
    short8 vB1 = *(const short8*)&vbase[voff + 48];
    f32x16 d1A = __builtin_amdgcn_mfma_f32_32x32x16_bf16(kfa, qf, z, 0, 0, 0);
    f32x16 d1B = __builtin_amdgcn_mfma_f32_32x32x16_bf16(kfb, qf, z, 0, 0, 0);

    int kpre = koff + 1024;
    int vpre = voff + 64;

#define SOFTMAX_PV(D1, V0, V1)                                                \
    {                                                                         \
        uint32_t pk0 = cvtpk(exp2_fast(D1[0]),  exp2_fast(D1[1]));            \
        uint32_t pk1 = cvtpk(exp2_fast(D1[2]),  exp2_fast(D1[3]));            \
        uint32_t pk2 = cvtpk(exp2_fast(D1[4]),  exp2_fast(D1[5]));            \
        uint32_t pk3 = cvtpk(exp2_fast(D1[6]),  exp2_fast(D1[7]));            \
        uint32_t pk4 = cvtpk(exp2_fast(D1[8]),  exp2_fast(D1[9]));            \
        uint32_t pk5 = cvtpk(exp2_fast(D1[10]), exp2_fast(D1[11]));           \
        uint32_t pk6 = cvtpk(exp2_fast(D1[12]), exp2_fast(D1[13]));           \
        uint32_t pk7 = cvtpk(exp2_fast(D1[14]), exp2_fast(D1[15]));           \
        permswap(pk0, pk2);                                                   \
        permswap(pk1, pk3);                                                   \
        permswap(pk4, pk6);                                                   \
        permswap(pk5, pk7);                                                   \
        union { uint32_t u[4]; short8 s; } A1_, A2_;                          \
        A1_.u[0] = pk0; A1_.u[1] = pk1; A1_.u[2] = pk2; A1_.u[3] = pk3;       \
        A2_.u[0] = pk4; A2_.u[1] = pk5; A2_.u[2] = pk6; A2_.u[3] = pk7;       \
        d2 = __builtin_amdgcn_mfma_f32_32x32x16_bf16(A1_.s, V0, d2, 0, 0, 0); \
        d2 = __builtin_amdgcn_mfma_f32_32x32x16_bf16(A2_.s, V1, d2, 0, 0, 0); \
    }

#pragma unroll 2
    for (int it = 0; it < 8; ++it) {
        kfa = *(const short8*)&kbase[kpre];
        SOFTMAX_PV(d1A, vA0, vA1)
        vA0 = *(const short8*)&vbase[vpre];
        vA1 = *(const short8*)&vbase[vpre + 16];
        d1A = __builtin_amdgcn_mfma_f32_32x32x16_bf16(kfa, qf, z, 0, 0, 0);
        kfb = *(const short8*)&kbase[kpre + 512];
        SOFTMAX_PV(d1B, vB0, vB1)
        vB0 = *(const short8*)&vbase[vpre + 32];
        vB1 = *(const short8*)&vbase[vpre + 48];
        d1B = __builtin_amdgcn_mfma_f32_32x32x16_bf16(kfb, qf, z, 0, 0, 0);
        kpre += 1024;
        vpre += 64;
    }
#undef SOFTMAX_PV

    if (sp > 0) {
        int w = sp - 1;
#pragma unroll
        for (int r = 0; r < 16; r++) {
            int row = (r & 3) + 8 * (r >> 2) + 4 * hi;
            lds_d2[h][w][row][tlo] = d2[r];   // O cols 0-15, lsum cols 16-31
        }
    }
    __syncthreads();
    if (sp == 0) {
        float v[16];
#pragma unroll
        for (int r = 0; r < 16; r++) {        // all lanes (shfl below)
            int row = (r & 3) + 8 * (r >> 2) + 4 * hi;
            float osum = d2[r] + lds_d2[h][0][row][tlo]
                       + lds_d2[h][1][row][tlo] + lds_d2[h][2][row][tlo];
            float rv = rcp_fast(osum);           // meaningful on lanes 16-31
            float rl = __shfl_xor(rv, 16, 64);   // O-lanes fetch rcp(lsum)
            v[r] = osum * rl;
        }
        if (tlo < 16) {
            int c = h * 16 + tlo;
#pragma unroll
            for (int r = 0; r < 16; r++) {
                int row = (r & 3) + 8 * (r >> 2) + 4 * hi;   // t index
                ostage[row * 68 + c] = bf16lo(v[r]);
            }
        }
    }
    __syncthreads();
    // proj GEMM by waves 1 and 5: out[o0+32 x t0+32] quadrants
    if (wv == 1 || wv == 5) {
        int o0 = (wv == 5) ? 32 : 0;
        int arow = o0 + tlo;
        f32x16 acc = {};
#pragma unroll
        for (int kk = 0; kk < 4; kk++) {
            int cb = kk * 16 + hi * 8;
            short8 af = *(const short8*)&wsh[arow * 64 + (cb ^ ((arow & 7) << 3))];
            union { uint2 u2[2]; short8 s; } B;
            B.u2[0] = *(const uint2*)&ostage[tlo * 68 + cb];
            B.u2[1] = *(const uint2*)&ostage[tlo * 68 + cb + 4];
            acc = __builtin_amdgcn_mfma_f32_32x32x16_bf16(af, B.s, acc, 0, 0, 0);
        }
#pragma unroll
        for (int r = 0; r < 16; r++) {
            int o = o0 + (r & 3) + 8 * (r >> 2) + 4 * hi;
            size_t idx = (size_t)(b * 64 + o) * LL + t0 + tlo;
            out[idx] = x[idx] + acc[r] + pb[o];
        }
    }
}

// ---------------------------------------------------------------------------
extern "C" void kernel_launch(void* const* d_in, const int* in_sizes, int n_in,
                              void* d_out, int out_size, void* d_ws, size_t ws_size,
                              hipStream_t stream) {
    const float* x   = (const float*)d_in[0];
    const float* gnw = (const float*)d_in[1];
    const float* gnb = (const float*)d_in[2];
    const float* qw  = (const float*)d_in[3];
    const float* qb  = (const float*)d_in[4];
    const float* pw  = (const float*)d_in[5];
    const float* pb  = (const float*)d_in[6];
    float* out = (float*)d_out;

    float* wsf   = (float*)d_ws;
    float* stats = wsf;                                  // 256 floats (partials)
    unsigned short* qt = (unsigned short*)(wsf + 256);   // 32*2048*16 bf16
    unsigned short* kt = qt + (size_t)32 * LL * 16;
    unsigned short* vb = kt + (size_t)32 * LL * 16;
    unsigned short* ones = vb + (size_t)32 * LL * 16;    // MUST follow vb
    unsigned short* wqb  = ones + 4096;                  // 12288 bf16 (qkv w)
    unsigned short* wpb  = wqb + 12288;                  // 4096 bf16 (proj w)

    hipLaunchKernelGGL(k_gnstats, dim3(128), dim3(256), 0, stream,
                       x, qw, pw, stats, ones, wqb);
    hipLaunchKernelGGL(k_qkv, dim3(32, 8), dim3(256), 0, stream,
                       x, gnw, gnb, wqb, qb, stats, qt, kt, vb);
    hipLaunchKernelGGL(k_attn, dim3(64, 8), dim3(1024), 0, stream,
                       qt, kt, vb, wpb, pb, x, out);
}